// Round 1
// baseline (6205.996 us; speedup 1.0000x reference)
//
#include <hip/hip_runtime.h>

#define BB 8
#define CC 64
#define NN 4096
#define OO 128
#define KNN 20
#define NCH 8
#define JCH (NN / NCH)  // 512
#define TJ 64
#define PITCH 68        // 68*4 B = 272 B, 16B-aligned rows, breaks bank conflicts

// ---------------------------------------------------------------------------
// Kernel 1: per-point precompute.
//   sqn[b][n]  = ||x_n||^2
//   A[b][n][o] = sum_c W[o][c]      * x[b][c][n]          (P)
//   Q[b][n][o] = sum_c W[o][64+c]*x - P + bias[o]          (G - P + b)
// ---------------------------------------------------------------------------
__global__ __launch_bounds__(256) void precompute_kernel(
    const float* __restrict__ x, const float* __restrict__ W,
    const float* __restrict__ bias, float* __restrict__ A,
    float* __restrict__ Q, float* __restrict__ sqn) {
  const int b = blockIdx.y;
  const int n = blockIdx.x * 256 + threadIdx.x;
  const float* xb = x + (size_t)b * CC * NN;

  float xr[CC];
  float sq = 0.f;
#pragma unroll
  for (int c = 0; c < CC; ++c) {
    xr[c] = xb[(size_t)c * NN + n];  // coalesced across threads
    sq = fmaf(xr[c], xr[c], sq);
  }
  sqn[(size_t)b * NN + n] = sq;

  float* Arow = A + ((size_t)b * NN + n) * OO;
  float* Qrow = Q + ((size_t)b * NN + n) * OO;

  for (int og = 0; og < OO; og += 4) {
    float p[4] = {0.f, 0.f, 0.f, 0.f};
    float g[4] = {0.f, 0.f, 0.f, 0.f};
#pragma unroll
    for (int oo = 0; oo < 4; ++oo) {
      const float* wr = W + (size_t)(og + oo) * (2 * CC);  // uniform -> s_load
#pragma unroll
      for (int c = 0; c < CC; c += 4) {
        float4 w1 = *(const float4*)(wr + c);
        float4 w2 = *(const float4*)(wr + CC + c);
        p[oo] = fmaf(w1.x, xr[c], p[oo]);
        p[oo] = fmaf(w1.y, xr[c + 1], p[oo]);
        p[oo] = fmaf(w1.z, xr[c + 2], p[oo]);
        p[oo] = fmaf(w1.w, xr[c + 3], p[oo]);
        g[oo] = fmaf(w2.x, xr[c], g[oo]);
        g[oo] = fmaf(w2.y, xr[c + 1], g[oo]);
        g[oo] = fmaf(w2.z, xr[c + 2], g[oo]);
        g[oo] = fmaf(w2.w, xr[c + 3], g[oo]);
      }
    }
    float4 pv = make_float4(p[0], p[1], p[2], p[3]);
    float4 qv = make_float4(g[0] - p[0] + bias[og + 0], g[1] - p[1] + bias[og + 1],
                            g[2] - p[2] + bias[og + 2], g[3] - p[3] + bias[og + 3]);
    *(float4*)(Arow + og) = pv;
    *(float4*)(Qrow + og) = qv;
  }
}

// ---------------------------------------------------------------------------
// Kernel 2: fused pairwise distance + per-chunk top-20.
// Thread = one query point i. Block = 256 i. Each block scans one j-chunk of
// 512, staging 64-j tiles in LDS. d_j = ||x_j||^2 - 2 x_i . x_j  (same
// ordering as reference pd). Sorted-insert with strict < keeps jax top_k's
// lower-index tie-break (j scanned ascending).
// ---------------------------------------------------------------------------
__global__ __launch_bounds__(256) void knn_kernel(
    const float* __restrict__ x, const float* __restrict__ sqn,
    float* __restrict__ cd, int* __restrict__ ci) {
  __shared__ float xj[TJ * PITCH];  // [j][c], pitch 68
  __shared__ float xxj[TJ];

  const int b = blockIdx.z;
  const int ch = blockIdx.y;
  const int i = blockIdx.x * 256 + threadIdx.x;
  const float* xb = x + (size_t)b * CC * NN;

  float xi[CC];
#pragma unroll
  for (int c = 0; c < CC; ++c) xi[c] = xb[(size_t)c * NN + i];

  float td[KNN];
  int ti[KNN];
#pragma unroll
  for (int k = 0; k < KNN; ++k) {
    td[k] = 1e30f;
    ti[k] = -1;
  }

  const int j0base = ch * JCH;
  for (int jt = 0; jt < JCH; jt += TJ) {
    const int j0 = j0base + jt;
    __syncthreads();
    // stage tile: coalesced global reads (j contiguous per c)
    for (int e = threadIdx.x; e < TJ * CC; e += 256) {
      const int jj = e & (TJ - 1);
      const int c = e >> 6;
      xj[jj * PITCH + c] = xb[(size_t)c * NN + j0 + jj];
    }
    if (threadIdx.x < TJ) xxj[threadIdx.x] = sqn[(size_t)b * NN + j0 + threadIdx.x];
    __syncthreads();

    for (int jj = 0; jj < TJ; ++jj) {
      const float* xp = xj + jj * PITCH;
      float a0 = 0.f, a1 = 0.f, a2 = 0.f, a3 = 0.f;
#pragma unroll
      for (int c = 0; c < CC; c += 4) {
        float4 v = *(const float4*)(xp + c);  // broadcast ds_read_b128
        a0 = fmaf(v.x, xi[c], a0);
        a1 = fmaf(v.y, xi[c + 1], a1);
        a2 = fmaf(v.z, xi[c + 2], a2);
        a3 = fmaf(v.w, xi[c + 3], a3);
      }
      const float dot = (a0 + a1) + (a2 + a3);
      const float d = fmaf(-2.f, dot, xxj[jj]);
      if (d < td[KNN - 1]) {
        td[KNN - 1] = d;
        ti[KNN - 1] = j0 + jj;
#pragma unroll
        for (int m = KNN - 1; m > 0; --m) {
          const bool sw = td[m] < td[m - 1];  // strict: stable on ties
          const float dl = sw ? td[m] : td[m - 1];
          const float dh = sw ? td[m - 1] : td[m];
          const int il = sw ? ti[m] : ti[m - 1];
          const int ih = sw ? ti[m - 1] : ti[m];
          td[m - 1] = dl;
          td[m] = dh;
          ti[m - 1] = il;
          ti[m] = ih;
        }
      }
    }
  }

  // candidate layout [b][ch][slot][i] -> coalesced writes & merge reads
  const size_t base = ((size_t)(b * NCH + ch) * KNN) * NN + i;
#pragma unroll
  for (int k = 0; k < KNN; ++k) {
    cd[base + (size_t)k * NN] = td[k];
    ci[base + (size_t)k * NN] = ti[k];
  }
}

// ---------------------------------------------------------------------------
// Kernel 3: merge 8 sorted 20-lists -> final top-20 indices.
// Chunks processed ascending (j-order), strict comparisons => exact reference
// tie semantics (value desc == dist asc, index asc).
// ---------------------------------------------------------------------------
__global__ __launch_bounds__(256) void merge_kernel(
    const float* __restrict__ cd, const int* __restrict__ ci,
    int* __restrict__ idxf) {
  const int b = blockIdx.y;
  const int n = blockIdx.x * 256 + threadIdx.x;

  float td[KNN];
  int ti[KNN];
#pragma unroll
  for (int k = 0; k < KNN; ++k) {
    td[k] = 1e30f;
    ti[k] = -1;
  }

  for (int ch = 0; ch < NCH; ++ch) {
    const size_t base = ((size_t)(b * NCH + ch) * KNN) * NN + n;
    for (int s = 0; s < KNN; ++s) {
      const float d = cd[base + (size_t)s * NN];
      if (!(d < td[KNN - 1])) break;  // chunk sorted: rest can't qualify
      const int j = ci[base + (size_t)s * NN];
      td[KNN - 1] = d;
      ti[KNN - 1] = j;
#pragma unroll
      for (int m = KNN - 1; m > 0; --m) {
        const bool sw = td[m] < td[m - 1];
        const float dl = sw ? td[m] : td[m - 1];
        const float dh = sw ? td[m - 1] : td[m];
        const int il = sw ? ti[m] : ti[m - 1];
        const int ih = sw ? ti[m - 1] : ti[m];
        td[m - 1] = dl;
        td[m] = dh;
        ti[m - 1] = il;
        ti[m] = ih;
      }
    }
  }

  for (int k = 0; k < KNN; ++k)
    idxf[((size_t)b * KNN + k) * NN + n] = ti[k];
}

// ---------------------------------------------------------------------------
// Kernel 4: gather + max + leaky + transposed store.
//   out[b][o][n] = leaky( Q[b][n][o] + max_k A[b][idx[n][k]][o] )
// (leaky is monotone, so max commutes past it; +Q is k-invariant.)
// ---------------------------------------------------------------------------
__global__ __launch_bounds__(128) void gather_kernel(
    const float* __restrict__ A, const float* __restrict__ Q,
    const int* __restrict__ idxf, float* __restrict__ out) {
  __shared__ int jidx[KNN][32];
  __shared__ float ob[32][OO + 1];  // pad -> conflict-free transpose

  const int b = blockIdx.y;
  const int n0 = blockIdx.x * 32;
  const int t = threadIdx.x;  // t = o channel

  for (int e = t; e < KNN * 32; e += 128) {
    const int k = e >> 5, ii = e & 31;
    jidx[k][ii] = idxf[((size_t)b * KNN + k) * NN + n0 + ii];
  }
  __syncthreads();

  const float* Ab = A + (size_t)b * NN * OO;
  const float* Qb = Q + (size_t)b * NN * OO;

  for (int ii = 0; ii < 32; ++ii) {
    float m = -1e30f;
#pragma unroll
    for (int k = 0; k < KNN; ++k) {
      m = fmaxf(m, Ab[(size_t)jidx[k][ii] * OO + t]);  // coalesced 512B gather
    }
    const float h = m + Qb[(size_t)(n0 + ii) * OO + t];
    ob[ii][t] = (h >= 0.f) ? h : 0.2f * h;
  }
  __syncthreads();

  float* ou = out + (size_t)b * OO * NN;
  for (int e = t; e < 32 * OO; e += 128) {
    const int ii = e & 31, oo = e >> 5;
    ou[(size_t)oo * NN + n0 + ii] = ob[ii][oo];  // coalesced 128B runs
  }
}

// ---------------------------------------------------------------------------
extern "C" void kernel_launch(void* const* d_in, const int* in_sizes, int n_in,
                              void* d_out, int out_size, void* d_ws,
                              size_t ws_size, hipStream_t stream) {
  (void)in_sizes;
  (void)n_in;
  (void)out_size;
  (void)ws_size;
  const float* x = (const float*)d_in[0];
  const float* W = (const float*)d_in[1];
  const float* bias = (const float*)d_in[2];
  float* out = (float*)d_out;

  char* ws = (char*)d_ws;
  size_t off = 0;
  float* A = (float*)(ws + off);
  off += (size_t)BB * NN * OO * 4;  // 16 MB
  float* Q = (float*)(ws + off);
  off += (size_t)BB * NN * OO * 4;  // 16 MB
  float* sqn = (float*)(ws + off);
  off += (size_t)BB * NN * 4;  // 128 KB
  float* cd = (float*)(ws + off);
  off += (size_t)BB * NCH * KNN * NN * 4;  // 21 MB
  int* ci = (int*)(ws + off);
  off += (size_t)BB * NCH * KNN * NN * 4;  // 21 MB
  int* idxf = (int*)(ws + off);
  off += (size_t)BB * KNN * NN * 4;  // 2.6 MB

  precompute_kernel<<<dim3(NN / 256, BB), 256, 0, stream>>>(x, W, bias, A, Q, sqn);
  knn_kernel<<<dim3(NN / 256, NCH, BB), 256, 0, stream>>>(x, sqn, cd, ci);
  merge_kernel<<<dim3(NN / 256, BB), 256, 0, stream>>>(cd, ci, idxf);
  gather_kernel<<<dim3(NN / 32, BB), 128, 0, stream>>>(A, Q, idxf, out);
}

// Round 2
// 5978.278 us; speedup vs baseline: 1.0381x; 1.0381x over previous
//
#include <hip/hip_runtime.h>

#define BB 8
#define CC 64
#define NN 4096
#define OO 128
#define KNN 20
#define NCH 8
#define JCH (NN / NCH)  // 512
#define TJ 64
#define PITCH 68        // 68*4 B = 272 B, 16B-aligned rows, breaks bank conflicts

// ---------------------------------------------------------------------------
// Kernel 1: per-point precompute.
//   sqn[b][n]  = ||x_n||^2
//   A[b][n][o] = sum_c W[o][c]      * x[b][c][n]          (P)
//   Q[b][n][o] = sum_c W[o][64+c]*x - P + bias[o]          (G - P + b)
// __launch_bounds__(256,3): needs ~90 live VGPRs (xr[64]+p/g+addr); cap 168
// avoids the heuristic 96-VGPR spill seen on knn.
// ---------------------------------------------------------------------------
__global__ __launch_bounds__(256, 3) void precompute_kernel(
    const float* __restrict__ x, const float* __restrict__ W,
    const float* __restrict__ bias, float* __restrict__ A,
    float* __restrict__ Q, float* __restrict__ sqn) {
  const int b = blockIdx.y;
  const int n = blockIdx.x * 256 + threadIdx.x;
  const float* xb = x + (size_t)b * CC * NN;

  float xr[CC];
  float sq = 0.f;
#pragma unroll
  for (int c = 0; c < CC; ++c) {
    xr[c] = xb[(size_t)c * NN + n];  // coalesced across threads
    sq = fmaf(xr[c], xr[c], sq);
  }
  sqn[(size_t)b * NN + n] = sq;

  float* Arow = A + ((size_t)b * NN + n) * OO;
  float* Qrow = Q + ((size_t)b * NN + n) * OO;

  for (int og = 0; og < OO; og += 4) {
    float p[4] = {0.f, 0.f, 0.f, 0.f};
    float g[4] = {0.f, 0.f, 0.f, 0.f};
#pragma unroll
    for (int oo = 0; oo < 4; ++oo) {
      const float* wr = W + (size_t)(og + oo) * (2 * CC);  // uniform -> s_load
#pragma unroll
      for (int c = 0; c < CC; c += 4) {
        float4 w1 = *(const float4*)(wr + c);
        float4 w2 = *(const float4*)(wr + CC + c);
        p[oo] = fmaf(w1.x, xr[c], p[oo]);
        p[oo] = fmaf(w1.y, xr[c + 1], p[oo]);
        p[oo] = fmaf(w1.z, xr[c + 2], p[oo]);
        p[oo] = fmaf(w1.w, xr[c + 3], p[oo]);
        g[oo] = fmaf(w2.x, xr[c], g[oo]);
        g[oo] = fmaf(w2.y, xr[c + 1], g[oo]);
        g[oo] = fmaf(w2.z, xr[c + 2], g[oo]);
        g[oo] = fmaf(w2.w, xr[c + 3], g[oo]);
      }
    }
    float4 pv = make_float4(p[0], p[1], p[2], p[3]);
    float4 qv = make_float4(g[0] - p[0] + bias[og + 0], g[1] - p[1] + bias[og + 1],
                            g[2] - p[2] + bias[og + 2], g[3] - p[3] + bias[og + 3]);
    *(float4*)(Arow + og) = pv;
    *(float4*)(Qrow + og) = qv;
  }
}

// ---------------------------------------------------------------------------
// Kernel 2: fused pairwise distance + per-chunk top-20.
// Thread = one query point i. Block = 256 i. Each block scans one j-chunk of
// 512, staging 64-j tiles in LDS. d_j = ||x_j||^2 - 2 x_i . x_j  (same
// ordering as reference pd). Sorted-insert with strict < keeps jax top_k's
// lower-index tie-break (j scanned ascending).
//
// __launch_bounds__(256, 3): live state = xi[64] + td/ti[40] + acc/addr
// ~= 130 VGPRs. Default heuristic chose 96 -> scratch spill in the inner
// loop (R1: 5.7 ms, VALUBusy 79% on spill traffic). Cap 512/3 = 168 VGPRs,
// 3 waves/SIMD (12 waves/CU).
// ---------------------------------------------------------------------------
__global__ __launch_bounds__(256, 3) void knn_kernel(
    const float* __restrict__ x, const float* __restrict__ sqn,
    float* __restrict__ cd, int* __restrict__ ci) {
  __shared__ float xj[TJ * PITCH];  // [j][c], pitch 68
  __shared__ float xxj[TJ];

  const int b = blockIdx.z;
  const int ch = blockIdx.y;
  const int i = blockIdx.x * 256 + threadIdx.x;
  const float* xb = x + (size_t)b * CC * NN;

  float xi[CC];
#pragma unroll
  for (int c = 0; c < CC; ++c) xi[c] = xb[(size_t)c * NN + i];

  float td[KNN];
  int ti[KNN];
#pragma unroll
  for (int k = 0; k < KNN; ++k) {
    td[k] = 1e30f;
    ti[k] = -1;
  }

  const int j0base = ch * JCH;
  for (int jt = 0; jt < JCH; jt += TJ) {
    const int j0 = j0base + jt;
    __syncthreads();
    // stage tile: coalesced global reads (j contiguous per c)
    for (int e = threadIdx.x; e < TJ * CC; e += 256) {
      const int jj = e & (TJ - 1);
      const int c = e >> 6;
      xj[jj * PITCH + c] = xb[(size_t)c * NN + j0 + jj];
    }
    if (threadIdx.x < TJ) xxj[threadIdx.x] = sqn[(size_t)b * NN + j0 + threadIdx.x];
    __syncthreads();

    for (int jj = 0; jj < TJ; ++jj) {
      const float* xp = xj + jj * PITCH;
      float a0 = 0.f, a1 = 0.f, a2 = 0.f, a3 = 0.f;
#pragma unroll
      for (int c = 0; c < CC; c += 4) {
        float4 v = *(const float4*)(xp + c);  // broadcast ds_read_b128
        a0 = fmaf(v.x, xi[c], a0);
        a1 = fmaf(v.y, xi[c + 1], a1);
        a2 = fmaf(v.z, xi[c + 2], a2);
        a3 = fmaf(v.w, xi[c + 3], a3);
      }
      const float dot = (a0 + a1) + (a2 + a3);
      const float d = fmaf(-2.f, dot, xxj[jj]);
      if (d < td[KNN - 1]) {
        td[KNN - 1] = d;
        ti[KNN - 1] = j0 + jj;
#pragma unroll
        for (int m = KNN - 1; m > 0; --m) {
          const bool sw = td[m] < td[m - 1];  // strict: stable on ties
          const float dl = sw ? td[m] : td[m - 1];
          const float dh = sw ? td[m - 1] : td[m];
          const int il = sw ? ti[m] : ti[m - 1];
          const int ih = sw ? ti[m - 1] : ti[m];
          td[m - 1] = dl;
          td[m] = dh;
          ti[m - 1] = il;
          ti[m] = ih;
        }
      }
    }
  }

  // candidate layout [b][ch][slot][i] -> coalesced writes & merge reads
  const size_t base = ((size_t)(b * NCH + ch) * KNN) * NN + i;
#pragma unroll
  for (int k = 0; k < KNN; ++k) {
    cd[base + (size_t)k * NN] = td[k];
    ci[base + (size_t)k * NN] = ti[k];
  }
}

// ---------------------------------------------------------------------------
// Kernel 3: merge 8 sorted 20-lists -> final top-20 indices.
// Chunks processed ascending (j-order), strict comparisons => exact reference
// tie semantics (value desc == dist asc, index asc).
// __launch_bounds__(256,3): td/ti + addr ~= 60 VGPRs live — keep cap roomy.
// ---------------------------------------------------------------------------
__global__ __launch_bounds__(256, 3) void merge_kernel(
    const float* __restrict__ cd, const int* __restrict__ ci,
    int* __restrict__ idxf) {
  const int b = blockIdx.y;
  const int n = blockIdx.x * 256 + threadIdx.x;

  float td[KNN];
  int ti[KNN];
#pragma unroll
  for (int k = 0; k < KNN; ++k) {
    td[k] = 1e30f;
    ti[k] = -1;
  }

  for (int ch = 0; ch < NCH; ++ch) {
    const size_t base = ((size_t)(b * NCH + ch) * KNN) * NN + n;
    for (int s = 0; s < KNN; ++s) {
      const float d = cd[base + (size_t)s * NN];
      if (!(d < td[KNN - 1])) break;  // chunk sorted: rest can't qualify
      const int j = ci[base + (size_t)s * NN];
      td[KNN - 1] = d;
      ti[KNN - 1] = j;
#pragma unroll
      for (int m = KNN - 1; m > 0; --m) {
        const bool sw = td[m] < td[m - 1];
        const float dl = sw ? td[m] : td[m - 1];
        const float dh = sw ? td[m - 1] : td[m];
        const int il = sw ? ti[m] : ti[m - 1];
        const int ih = sw ? ti[m - 1] : ti[m];
        td[m - 1] = dl;
        td[m] = dh;
        ti[m - 1] = il;
        ti[m] = ih;
      }
    }
  }

  for (int k = 0; k < KNN; ++k)
    idxf[((size_t)b * KNN + k) * NN + n] = ti[k];
}

// ---------------------------------------------------------------------------
// Kernel 4: gather + max + leaky + transposed store.
//   out[b][o][n] = leaky( Q[b][n][o] + max_k A[b][idx[n][k]][o] )
// (leaky is monotone, so max commutes past it; +Q is k-invariant.)
// ---------------------------------------------------------------------------
__global__ __launch_bounds__(128) void gather_kernel(
    const float* __restrict__ A, const float* __restrict__ Q,
    const int* __restrict__ idxf, float* __restrict__ out) {
  __shared__ int jidx[KNN][32];
  __shared__ float ob[32][OO + 1];  // pad -> conflict-free transpose

  const int b = blockIdx.y;
  const int n0 = blockIdx.x * 32;
  const int t = threadIdx.x;  // t = o channel

  for (int e = t; e < KNN * 32; e += 128) {
    const int k = e >> 5, ii = e & 31;
    jidx[k][ii] = idxf[((size_t)b * KNN + k) * NN + n0 + ii];
  }
  __syncthreads();

  const float* Ab = A + (size_t)b * NN * OO;
  const float* Qb = Q + (size_t)b * NN * OO;

  for (int ii = 0; ii < 32; ++ii) {
    float m = -1e30f;
#pragma unroll
    for (int k = 0; k < KNN; ++k) {
      m = fmaxf(m, Ab[(size_t)jidx[k][ii] * OO + t]);  // coalesced 512B gather
    }
    const float h = m + Qb[(size_t)(n0 + ii) * OO + t];
    ob[ii][t] = (h >= 0.f) ? h : 0.2f * h;
  }
  __syncthreads();

  float* ou = out + (size_t)b * OO * NN;
  for (int e = t; e < 32 * OO; e += 128) {
    const int ii = e & 31, oo = e >> 5;
    ou[(size_t)oo * NN + n0 + ii] = ob[ii][oo];  // coalesced 128B runs
  }
}

// ---------------------------------------------------------------------------
extern "C" void kernel_launch(void* const* d_in, const int* in_sizes, int n_in,
                              void* d_out, int out_size, void* d_ws,
                              size_t ws_size, hipStream_t stream) {
  (void)in_sizes;
  (void)n_in;
  (void)out_size;
  (void)ws_size;
  const float* x = (const float*)d_in[0];
  const float* W = (const float*)d_in[1];
  const float* bias = (const float*)d_in[2];
  float* out = (float*)d_out;

  char* ws = (char*)d_ws;
  size_t off = 0;
  float* A = (float*)(ws + off);
  off += (size_t)BB * NN * OO * 4;  // 16 MB
  float* Q = (float*)(ws + off);
  off += (size_t)BB * NN * OO * 4;  // 16 MB
  float* sqn = (float*)(ws + off);
  off += (size_t)BB * NN * 4;  // 128 KB
  float* cd = (float*)(ws + off);
  off += (size_t)BB * NCH * KNN * NN * 4;  // 21 MB
  int* ci = (int*)(ws + off);
  off += (size_t)BB * NCH * KNN * NN * 4;  // 21 MB
  int* idxf = (int*)(ws + off);
  off += (size_t)BB * KNN * NN * 4;  // 2.6 MB

  precompute_kernel<<<dim3(NN / 256, BB), 256, 0, stream>>>(x, W, bias, A, Q, sqn);
  knn_kernel<<<dim3(NN / 256, NCH, BB), 256, 0, stream>>>(x, sqn, cd, ci);
  merge_kernel<<<dim3(NN / 256, BB), 256, 0, stream>>>(cd, ci, idxf);
  gather_kernel<<<dim3(NN / 32, BB), 128, 0, stream>>>(A, Q, idxf, out);
}

// Round 3
// 1194.731 us; speedup vs baseline: 5.1945x; 5.0039x over previous
//
#include <hip/hip_runtime.h>

#define BB 8
#define CC 64
#define NN 4096
#define OO 128
#define KNN 20
#define NCH 8
#define JCH (NN / NCH)  // 512
#define TJ 64
#define PITCH 68        // 68*4 B = 272 B, 16B-aligned rows, breaks bank conflicts

// ---------------------------------------------------------------------------
// Top-20 state as NAMED SCALARS. R2 evidence: td[20]/ti[20] arrays were never
// SROA-promoted (merge_kernel VGPR_Count=28 < 40 live values => alloca in
// scratch; knn paid 40 scratch ops per inserted j-step -> 50 GB HBM FETCH).
// Named scalars are SSA values; promotion is unconditional.
// ---------------------------------------------------------------------------
#define TK_LIST(OP) OP(0) OP(1) OP(2) OP(3) OP(4) OP(5) OP(6) OP(7) OP(8) \
    OP(9) OP(10) OP(11) OP(12) OP(13) OP(14) OP(15) OP(16) OP(17) OP(18) OP(19)

#define TK_DECL(k) float td##k = 1e30f; int ti##k = -1;

// strict <: stable on ties (earlier-inserted = lower j wins), matches jax
// top_k tie-break given ascending-j scan. Identical semantics to the array
// version that passed R1/R2 (absmax 0.015625).
#define TK_SW(a, b)                                                        \
  {                                                                        \
    const bool _s = td##b < td##a;                                         \
    const float _fa = _s ? td##b : td##a;                                  \
    const float _fb = _s ? td##a : td##b;                                  \
    const int _ia = _s ? ti##b : ti##a;                                    \
    const int _ib = _s ? ti##a : ti##b;                                    \
    td##a = _fa; td##b = _fb; ti##a = _ia; ti##b = _ib;                    \
  }

#define TK_BUBBLE                                                          \
  TK_SW(18, 19) TK_SW(17, 18) TK_SW(16, 17) TK_SW(15, 16) TK_SW(14, 15)    \
  TK_SW(13, 14) TK_SW(12, 13) TK_SW(11, 12) TK_SW(10, 11) TK_SW(9, 10)     \
  TK_SW(8, 9) TK_SW(7, 8) TK_SW(6, 7) TK_SW(5, 6) TK_SW(4, 5)              \
  TK_SW(3, 4) TK_SW(2, 3) TK_SW(1, 2) TK_SW(0, 1)

// ---------------------------------------------------------------------------
// Kernel 1: per-point precompute.
//   sqn[b][n]  = ||x_n||^2
//   A[b][n][o] = sum_c W[o][c]      * x[b][c][n]          (P)
//   Q[b][n][o] = sum_c W[o][64+c]*x - P + bias[o]          (G - P + b)
// ---------------------------------------------------------------------------
__global__ __launch_bounds__(256, 3) void precompute_kernel(
    const float* __restrict__ x, const float* __restrict__ W,
    const float* __restrict__ bias, float* __restrict__ A,
    float* __restrict__ Q, float* __restrict__ sqn) {
  const int b = blockIdx.y;
  const int n = blockIdx.x * 256 + threadIdx.x;
  const float* xb = x + (size_t)b * CC * NN;

  float xr[CC];
  float sq = 0.f;
#pragma unroll
  for (int c = 0; c < CC; ++c) {
    xr[c] = xb[(size_t)c * NN + n];  // coalesced across threads
    sq = fmaf(xr[c], xr[c], sq);
  }
  sqn[(size_t)b * NN + n] = sq;

  float* Arow = A + ((size_t)b * NN + n) * OO;
  float* Qrow = Q + ((size_t)b * NN + n) * OO;

  for (int og = 0; og < OO; og += 4) {
    float p[4] = {0.f, 0.f, 0.f, 0.f};
    float g[4] = {0.f, 0.f, 0.f, 0.f};
#pragma unroll
    for (int oo = 0; oo < 4; ++oo) {
      const float* wr = W + (size_t)(og + oo) * (2 * CC);  // uniform -> s_load
#pragma unroll
      for (int c = 0; c < CC; c += 4) {
        float4 w1 = *(const float4*)(wr + c);
        float4 w2 = *(const float4*)(wr + CC + c);
        p[oo] = fmaf(w1.x, xr[c], p[oo]);
        p[oo] = fmaf(w1.y, xr[c + 1], p[oo]);
        p[oo] = fmaf(w1.z, xr[c + 2], p[oo]);
        p[oo] = fmaf(w1.w, xr[c + 3], p[oo]);
        g[oo] = fmaf(w2.x, xr[c], g[oo]);
        g[oo] = fmaf(w2.y, xr[c + 1], g[oo]);
        g[oo] = fmaf(w2.z, xr[c + 2], g[oo]);
        g[oo] = fmaf(w2.w, xr[c + 3], g[oo]);
      }
    }
    float4 pv = make_float4(p[0], p[1], p[2], p[3]);
    float4 qv = make_float4(g[0] - p[0] + bias[og + 0], g[1] - p[1] + bias[og + 1],
                            g[2] - p[2] + bias[og + 2], g[3] - p[3] + bias[og + 3]);
    *(float4*)(Arow + og) = pv;
    *(float4*)(Qrow + og) = qv;
  }
}

// ---------------------------------------------------------------------------
// Kernel 2: fused pairwise distance + per-chunk top-20.
// Thread = one query point i. Block = 256 i. Each block scans one j-chunk of
// 512, staging 64-j tiles in LDS. d_j = ||x_j||^2 - 2 x_i . x_j  (same
// ordering as reference pd). Scalar top-20 (see TK_* above).
// ---------------------------------------------------------------------------
__global__ __launch_bounds__(256, 3) void knn_kernel(
    const float* __restrict__ x, const float* __restrict__ sqn,
    float* __restrict__ cd, int* __restrict__ ci) {
  __shared__ float xj[TJ * PITCH];  // [j][c], pitch 68
  __shared__ float xxj[TJ];

  const int b = blockIdx.z;
  const int ch = blockIdx.y;
  const int i = blockIdx.x * 256 + threadIdx.x;
  const float* xb = x + (size_t)b * CC * NN;

  float xi[CC];
#pragma unroll
  for (int c = 0; c < CC; ++c) xi[c] = xb[(size_t)c * NN + i];

  TK_LIST(TK_DECL)

  const int j0base = ch * JCH;
  for (int jt = 0; jt < JCH; jt += TJ) {
    const int j0 = j0base + jt;
    __syncthreads();
    // stage tile: coalesced global reads (j contiguous per c)
    for (int e = threadIdx.x; e < TJ * CC; e += 256) {
      const int jj = e & (TJ - 1);
      const int c = e >> 6;
      xj[jj * PITCH + c] = xb[(size_t)c * NN + j0 + jj];
    }
    if (threadIdx.x < TJ) xxj[threadIdx.x] = sqn[(size_t)b * NN + j0 + threadIdx.x];
    __syncthreads();

    for (int jj = 0; jj < TJ; ++jj) {
      const float* xp = xj + jj * PITCH;
      float a0 = 0.f, a1 = 0.f, a2 = 0.f, a3 = 0.f;
#pragma unroll
      for (int c = 0; c < CC; c += 4) {
        float4 v = *(const float4*)(xp + c);  // broadcast ds_read_b128
        a0 = fmaf(v.x, xi[c], a0);
        a1 = fmaf(v.y, xi[c + 1], a1);
        a2 = fmaf(v.z, xi[c + 2], a2);
        a3 = fmaf(v.w, xi[c + 3], a3);
      }
      const float dot = (a0 + a1) + (a2 + a3);
      const float d = fmaf(-2.f, dot, xxj[jj]);
      if (d < td19) {
        td19 = d;
        ti19 = j0 + jj;
        TK_BUBBLE
      }
    }
  }

  // candidate layout [b][ch][slot][i] -> coalesced writes & merge reads
  const size_t base = ((size_t)(b * NCH + ch) * KNN) * NN + i;
#define TK_STORE(k)                                                        \
  cd[base + (size_t)(k) * NN] = td##k;                                     \
  ci[base + (size_t)(k) * NN] = ti##k;
  TK_LIST(TK_STORE)
#undef TK_STORE
}

// ---------------------------------------------------------------------------
// Kernel 3: merge 8 sorted 20-lists -> final top-20 indices.
// Chunks processed ascending (j-order), strict comparisons => exact reference
// tie semantics (value desc == dist asc, index asc).
// ---------------------------------------------------------------------------
__global__ __launch_bounds__(256, 3) void merge_kernel(
    const float* __restrict__ cd, const int* __restrict__ ci,
    int* __restrict__ idxf) {
  const int b = blockIdx.y;
  const int n = blockIdx.x * 256 + threadIdx.x;

  TK_LIST(TK_DECL)

  for (int ch = 0; ch < NCH; ++ch) {
    const size_t base = ((size_t)(b * NCH + ch) * KNN) * NN + n;
    for (int s = 0; s < KNN; ++s) {
      const float d = cd[base + (size_t)s * NN];
      if (!(d < td19)) break;  // chunk sorted: rest can't qualify
      const int j = ci[base + (size_t)s * NN];
      td19 = d;
      ti19 = j;
      TK_BUBBLE
    }
  }

#define TK_STI(k) idxf[((size_t)b * KNN + (k)) * NN + n] = ti##k;
  TK_LIST(TK_STI)
#undef TK_STI
}

// ---------------------------------------------------------------------------
// Kernel 4: gather + max + leaky + transposed store.
//   out[b][o][n] = leaky( Q[b][n][o] + max_k A[b][idx[n][k]][o] )
// (leaky is monotone, so max commutes past it; +Q is k-invariant.)
// ---------------------------------------------------------------------------
__global__ __launch_bounds__(128) void gather_kernel(
    const float* __restrict__ A, const float* __restrict__ Q,
    const int* __restrict__ idxf, float* __restrict__ out) {
  __shared__ int jidx[KNN][32];
  __shared__ float ob[32][OO + 1];  // pad -> conflict-free transpose

  const int b = blockIdx.y;
  const int n0 = blockIdx.x * 32;
  const int t = threadIdx.x;  // t = o channel

  for (int e = t; e < KNN * 32; e += 128) {
    const int k = e >> 5, ii = e & 31;
    jidx[k][ii] = idxf[((size_t)b * KNN + k) * NN + n0 + ii];
  }
  __syncthreads();

  const float* Ab = A + (size_t)b * NN * OO;
  const float* Qb = Q + (size_t)b * NN * OO;

  for (int ii = 0; ii < 32; ++ii) {
    float m = -1e30f;
#pragma unroll
    for (int k = 0; k < KNN; ++k) {
      m = fmaxf(m, Ab[(size_t)jidx[k][ii] * OO + t]);  // coalesced 512B gather
    }
    const float h = m + Qb[(size_t)(n0 + ii) * OO + t];
    ob[ii][t] = (h >= 0.f) ? h : 0.2f * h;
  }
  __syncthreads();

  float* ou = out + (size_t)b * OO * NN;
  for (int e = t; e < 32 * OO; e += 128) {
    const int ii = e & 31, oo = e >> 5;
    ou[(size_t)oo * NN + n0 + ii] = ob[ii][oo];  // coalesced 128B runs
  }
}

// ---------------------------------------------------------------------------
extern "C" void kernel_launch(void* const* d_in, const int* in_sizes, int n_in,
                              void* d_out, int out_size, void* d_ws,
                              size_t ws_size, hipStream_t stream) {
  (void)in_sizes;
  (void)n_in;
  (void)out_size;
  (void)ws_size;
  const float* x = (const float*)d_in[0];
  const float* W = (const float*)d_in[1];
  const float* bias = (const float*)d_in[2];
  float* out = (float*)d_out;

  char* ws = (char*)d_ws;
  size_t off = 0;
  float* A = (float*)(ws + off);
  off += (size_t)BB * NN * OO * 4;  // 16 MB
  float* Q = (float*)(ws + off);
  off += (size_t)BB * NN * OO * 4;  // 16 MB
  float* sqn = (float*)(ws + off);
  off += (size_t)BB * NN * 4;  // 128 KB
  float* cd = (float*)(ws + off);
  off += (size_t)BB * NCH * KNN * NN * 4;  // 21 MB
  int* ci = (int*)(ws + off);
  off += (size_t)BB * NCH * KNN * NN * 4;  // 21 MB
  int* idxf = (int*)(ws + off);
  off += (size_t)BB * KNN * NN * 4;  // 2.6 MB

  precompute_kernel<<<dim3(NN / 256, BB), 256, 0, stream>>>(x, W, bias, A, Q, sqn);
  knn_kernel<<<dim3(NN / 256, NCH, BB), 256, 0, stream>>>(x, sqn, cd, ci);
  merge_kernel<<<dim3(NN / 256, BB), 256, 0, stream>>>(cd, ci, idxf);
  gather_kernel<<<dim3(NN / 32, BB), 128, 0, stream>>>(A, Q, idxf, out);
}